// Round 11
// baseline (83.029 us; speedup 1.0000x reference)
//
#include <hip/hip_runtime.h>
#include <math.h>

// Hexagonal sensor photon binning — R11: atomic-free flush.
// R10 finding: WRITE_SIZE == nblocks*1801*4B exactly => every flush atomicAdd
// is a 4B write-through HBM transaction (3.7M scattered masked writes ~= 236MB
// of effective controller work). Fix: each block STORES its hist to a private
// d_ws row (coalesced full-line writes), then a 2D reduce kernel sums rows
// with one atomic per (pixel, rowgroup) — 64x fewer atomics.
//  * main loop = R9 (2-deep SW pipeline, nt 16B loads, closed-form hex index)
//  * per-block LDS histogram

typedef float f32x4 __attribute__((ext_vector_type(4)));

#define BIN_BLOCKS 2048
#define RED_ROWS   64     // rows summed per reduce block

__global__ void hex_zero_kernel(float* __restrict__ p, int n) {
    int i = blockIdx.x * blockDim.x + threadIdx.x;
    if (i < n) p[i] = 0.0f;
}

// partials: [nrows][n_pixels]; each block sums RED_ROWS rows for 256 pixels.
__global__ __launch_bounds__(256) void hex_reduce_kernel(
    const float* __restrict__ partials, float* __restrict__ out,
    int n_pixels, int nrows)
{
    int pix = blockIdx.x * blockDim.x + threadIdx.x;
    if (pix >= n_pixels) return;
    int r0 = blockIdx.y * RED_ROWS;
    int r1 = min(r0 + RED_ROWS, nrows);
    float s = 0.0f;
    const float* p = partials + (size_t)r0 * n_pixels + pix;
    #pragma unroll 8
    for (int r = r0; r < r1; ++r) {
        s += *p;
        p += n_pixels;
    }
    atomicAdd(&out[pix], s);
}

__global__ __launch_bounds__(256) void hex_bin_kernel(
    const float* __restrict__ x,
    const float* __restrict__ y,
    const float* __restrict__ vals,
    const float* __restrict__ hex_size_p,
    const float* __restrict__ q_off_p,
    const float* __restrict__ r_off_p,
    const int*   __restrict__ q_min_p,
    const int*   __restrict__ r_min_p,
    int Rh, int n_pixels, int n_photons,
    float* __restrict__ flush_dst,
    int flush_mode)   // 2 = private row store, 1 = 64-row atomic, 0 = direct atomic
{
    extern __shared__ float hist[];  // n_pixels floats
    for (int i = threadIdx.x; i < n_pixels; i += blockDim.x) hist[i] = 0.0f;
    __syncthreads();

    const float inv_h = 1.0f / hex_size_p[0];
    const float A  = 0.57735026918962576f * inv_h;
    const float Bn = -(0.33333333333333333f * inv_h);
    const float C  = 0.66666666666666667f * inv_h;
    const float qc = -q_off_p[0];
    const float rc = -r_off_p[0];
    const int   qmin = q_min_p[0];
    const int   rmin = r_min_p[0];

    const unsigned twoR = (unsigned)(2 * Rh);
    const int Rp1 = Rh + 1;

    auto process = [&](float xf, float yf, float vf) {
        float q = fmaf(A, xf, fmaf(Bn, yf, qc));
        float r = fmaf(C, yf, rc);
        float t = q + r;                  // s = -t, sr = -rintf(t)
        float qr = rintf(q);
        float rr = rintf(r);
        float tr = rintf(t);
        float qd = fabsf(qr - q);
        float rd = fabsf(rr - r);
        float td = fabsf(tr - t);         // == sd
        float q2 = (qd > rd && qd > td) ? (tr - rr) : qr;
        float r2 = (rd > qd && rd > td) ? (tr - qr) : rr;
        int qi = (int)q2 - qmin;
        int ri = (int)r2 - rmin;
        int d  = qi + ri;
        if ((unsigned)qi <= twoR && (unsigned)ri <= twoR &&
            (unsigned)(d - Rh) <= twoR) {
            int u  = max(qi - Rh, 0);
            int p  = qi * Rp1 + ((qi * qi - qi) >> 1) + d - Rh - u * u;
            atomicAdd(&hist[p], vf);      // ds_add_f32 (no return)
        }
    };

    const int tid    = blockIdx.x * blockDim.x + threadIdx.x;
    const int stride = gridDim.x * blockDim.x;
    const int n8     = n_photons >> 3;

    const f32x4* __restrict__ x4 = (const f32x4*)x;
    const f32x4* __restrict__ y4 = (const f32x4*)y;
    const f32x4* __restrict__ v4 = (const f32x4*)vals;

    // ---- 2-stage software pipeline ----
    f32x4 xa, xb, ya, yb, va, vb;
    int i = tid;
    if (i < n8) {
        int a = 2 * i, b = a + 1;
        xa = __builtin_nontemporal_load(&x4[a]);
        xb = __builtin_nontemporal_load(&x4[b]);
        ya = __builtin_nontemporal_load(&y4[a]);
        yb = __builtin_nontemporal_load(&y4[b]);
        va = __builtin_nontemporal_load(&v4[a]);
        vb = __builtin_nontemporal_load(&v4[b]);
    }
    while (i < n8) {
        int nx = i + stride;
        f32x4 nxa, nxb, nya, nyb, nva, nvb;
        bool has_next = nx < n8;
        if (has_next) {
            int a = 2 * nx, b = a + 1;
            nxa = __builtin_nontemporal_load(&x4[a]);
            nxb = __builtin_nontemporal_load(&x4[b]);
            nya = __builtin_nontemporal_load(&y4[a]);
            nyb = __builtin_nontemporal_load(&y4[b]);
            nva = __builtin_nontemporal_load(&v4[a]);
            nvb = __builtin_nontemporal_load(&v4[b]);
        }
        process(xa.x, ya.x, va.x);
        process(xa.y, ya.y, va.y);
        process(xa.z, ya.z, va.z);
        process(xa.w, ya.w, va.w);
        process(xb.x, yb.x, vb.x);
        process(xb.y, yb.y, vb.y);
        process(xb.z, yb.z, vb.z);
        process(xb.w, yb.w, vb.w);
        if (has_next) {
            xa = nxa; xb = nxb; ya = nya; yb = nyb; va = nva; vb = nvb;
        }
        i = nx;
    }
    for (int t2 = (n8 << 3) + tid; t2 < n_photons; t2 += stride) {
        process(x[t2], y[t2], vals[t2]);
    }

    __syncthreads();
    if (flush_mode == 2) {
        // private row: pure coalesced stores, no atomics, no zeroing needed
        float* dst = flush_dst + (size_t)blockIdx.x * n_pixels;
        for (int k = threadIdx.x; k < n_pixels; k += blockDim.x)
            dst[k] = hist[k];
    } else if (flush_mode == 1) {
        float* dst = flush_dst + (size_t)(blockIdx.x & 63) * n_pixels;
        for (int k = threadIdx.x; k < n_pixels; k += blockDim.x) {
            float h = hist[k];
            if (h != 0.0f) atomicAdd(&dst[k], h);
        }
    } else {
        for (int k = threadIdx.x; k < n_pixels; k += blockDim.x) {
            float h = hist[k];
            if (h != 0.0f) atomicAdd(&flush_dst[k], h);
        }
    }
}

extern "C" void kernel_launch(void* const* d_in, const int* in_sizes, int n_in,
                              void* d_out, int out_size, void* d_ws, size_t ws_size,
                              hipStream_t stream) {
    const float* x      = (const float*)d_in[0];
    const float* y      = (const float*)d_in[1];
    const float* vals   = (const float*)d_in[2];
    const float* hexs   = (const float*)d_in[4];
    const float* qoff   = (const float*)d_in[5];
    const float* roff   = (const float*)d_in[6];
    const int*   qmin   = (const int*)d_in[7];
    const int*   rmin   = (const int*)d_in[8];

    const int n_photons = in_sizes[0];
    const int lut_elems = in_sizes[3];
    const int Q  = (int)(0.5 + sqrt((double)lut_elems));  // 49
    const int Rh = (Q - 1) / 2;                           // 24
    const int n_pixels = out_size;

    float* out = (float*)d_out;
    float* partials = (float*)d_ws;

    const int threads = 256;
    const int blocks  = BIN_BLOCKS;
    const size_t lds_bytes = (size_t)n_pixels * sizeof(float);

    const size_t full_elems = (size_t)blocks * (size_t)n_pixels;
    const size_t p64_elems  = (size_t)64 * (size_t)n_pixels;

    if (ws_size >= full_elems * sizeof(float)) {
        // out must be zeroed (reduce atomics accumulate into it)
        hex_zero_kernel<<<(n_pixels + 255) / 256, 256, 0, stream>>>(out, n_pixels);
        hex_bin_kernel<<<blocks, threads, lds_bytes, stream>>>(
            x, y, vals, hexs, qoff, roff, qmin, rmin,
            Rh, n_pixels, n_photons, partials, 2);
        dim3 rgrid((n_pixels + 255) / 256, blocks / RED_ROWS);
        hex_reduce_kernel<<<rgrid, 256, 0, stream>>>(partials, out, n_pixels, blocks);
    } else if (ws_size >= p64_elems * sizeof(float)) {
        int zn = (int)p64_elems;
        hex_zero_kernel<<<(zn + 255) / 256, 256, 0, stream>>>(partials, zn);
        hex_zero_kernel<<<(n_pixels + 255) / 256, 256, 0, stream>>>(out, n_pixels);
        hex_bin_kernel<<<blocks, threads, lds_bytes, stream>>>(
            x, y, vals, hexs, qoff, roff, qmin, rmin,
            Rh, n_pixels, n_photons, partials, 1);
        dim3 rgrid((n_pixels + 255) / 256, 1);
        hex_reduce_kernel<<<rgrid, 256, 0, stream>>>(partials, out, n_pixels, 64);
    } else {
        hex_zero_kernel<<<(n_pixels + 255) / 256, 256, 0, stream>>>(out, n_pixels);
        hex_bin_kernel<<<blocks, threads, lds_bytes, stream>>>(
            x, y, vals, hexs, qoff, roff, qmin, rmin,
            Rh, n_pixels, n_photons, out, 0);
    }
}

// Round 12
// 74.045 us; speedup vs baseline: 1.1213x; 1.1213x over previous
//
#include <hip/hip_runtime.h>
#include <math.h>

// Hexagonal sensor photon binning — R12: block-chunked contiguous streaming.
// R6-R11 null results (every pipe <30% busy, bench pinned 78-83us regardless of
// occupancy/VALU/MLP/flush changes) point at address locality: grid-stride had
// each thread stepping 8.4MB per iteration, so every wave touched fresh DRAM
// rows/TLB pages and each CU swept the whole 240MB. Fix: each block owns a
// CONTIGUOUS chunk; per iteration a block reads 16KB contiguous per stream.
//  * 512 blocks x 1024 threads (32 waves/CU), partials 3.7MB (4x smaller)
//  * 2-deep SW pipeline + nt 16B loads, closed-form hex index, LDS hist
//  * store-flush to private rows + rowgroup reduce (no atomics in bin kernel)

typedef float f32x4 __attribute__((ext_vector_type(4)));

#define BIN_BLOCKS  512
#define BIN_THREADS 1024
#define RED_GROUP   32    // rows per reduce block

__global__ void hex_zero_kernel(float* __restrict__ p, int n) {
    int i = blockIdx.x * blockDim.x + threadIdx.x;
    if (i < n) p[i] = 0.0f;
}

__global__ __launch_bounds__(256) void hex_reduce_kernel(
    const float* __restrict__ partials, float* __restrict__ out,
    int n_pixels, int nrows)
{
    int pix = blockIdx.x * blockDim.x + threadIdx.x;
    if (pix >= n_pixels) return;
    int r0 = blockIdx.y * RED_GROUP;
    int r1 = min(r0 + RED_GROUP, nrows);
    float s = 0.0f;
    const float* p = partials + (size_t)r0 * n_pixels + pix;
    #pragma unroll 8
    for (int r = r0; r < r1; ++r) {
        s += *p;
        p += n_pixels;
    }
    atomicAdd(&out[pix], s);
}

__global__ __launch_bounds__(BIN_THREADS) void hex_bin_kernel(
    const float* __restrict__ x,
    const float* __restrict__ y,
    const float* __restrict__ vals,
    const float* __restrict__ hex_size_p,
    const float* __restrict__ q_off_p,
    const float* __restrict__ r_off_p,
    const int*   __restrict__ q_min_p,
    const int*   __restrict__ r_min_p,
    int Rh, int n_pixels, int n_photons,
    float* __restrict__ flush_dst,
    int flush_mode)   // 2 = private row store, 0 = direct atomic fallback
{
    extern __shared__ float hist[];  // n_pixels floats
    for (int i = threadIdx.x; i < n_pixels; i += blockDim.x) hist[i] = 0.0f;
    __syncthreads();

    const float inv_h = 1.0f / hex_size_p[0];
    const float A  = 0.57735026918962576f * inv_h;
    const float Bn = -(0.33333333333333333f * inv_h);
    const float C  = 0.66666666666666667f * inv_h;
    const float qc = -q_off_p[0];
    const float rc = -r_off_p[0];
    const int   qmin = q_min_p[0];
    const int   rmin = r_min_p[0];

    const unsigned twoR = (unsigned)(2 * Rh);
    const int Rp1 = Rh + 1;

    auto process = [&](float xf, float yf, float vf) {
        float q = fmaf(A, xf, fmaf(Bn, yf, qc));
        float r = fmaf(C, yf, rc);
        float t = q + r;                  // s = -t, sr = -rintf(t)
        float qr = rintf(q);
        float rr = rintf(r);
        float tr = rintf(t);
        float qd = fabsf(qr - q);
        float rd = fabsf(rr - r);
        float td = fabsf(tr - t);         // == sd
        float q2 = (qd > rd && qd > td) ? (tr - rr) : qr;
        float r2 = (rd > qd && rd > td) ? (tr - qr) : rr;
        int qi = (int)q2 - qmin;
        int ri = (int)r2 - rmin;
        int d  = qi + ri;
        if ((unsigned)qi <= twoR && (unsigned)ri <= twoR &&
            (unsigned)(d - Rh) <= twoR) {
            int u  = max(qi - Rh, 0);
            int p  = qi * Rp1 + ((qi * qi - qi) >> 1) + d - Rh - u * u;
            atomicAdd(&hist[p], vf);      // ds_add_f32 (no return)
        }
    };

    const int n4 = n_photons >> 2;       // 4-photon groups
    const f32x4* __restrict__ px = (const f32x4*)x;
    const f32x4* __restrict__ py = (const f32x4*)y;
    const f32x4* __restrict__ pv = (const f32x4*)vals;

    // ---- block-chunked contiguous walk ----
    const int C4 = (n4 + gridDim.x - 1) / gridDim.x;   // groups per block
    const int g0 = blockIdx.x * C4;
    const int g1 = min(g0 + C4, n4);

    // 2-stage software pipeline over g += blockDim.x
    int g = g0 + threadIdx.x;
    f32x4 xa, ya, va;
    if (g < g1) {
        xa = __builtin_nontemporal_load(&px[g]);
        ya = __builtin_nontemporal_load(&py[g]);
        va = __builtin_nontemporal_load(&pv[g]);
    }
    while (g < g1) {
        int gn = g + blockDim.x;
        f32x4 nx, ny, nv;
        bool has_next = gn < g1;
        if (has_next) {
            nx = __builtin_nontemporal_load(&px[gn]);
            ny = __builtin_nontemporal_load(&py[gn]);
            nv = __builtin_nontemporal_load(&pv[gn]);
        }
        process(xa.x, ya.x, va.x);
        process(xa.y, ya.y, va.y);
        process(xa.z, ya.z, va.z);
        process(xa.w, ya.w, va.w);
        if (has_next) { xa = nx; ya = ny; va = nv; }
        g = gn;
    }

    // photon tail (n_photons % 4)
    {
        int t0 = (n4 << 2) + blockIdx.x * blockDim.x + threadIdx.x;
        int ts = gridDim.x * blockDim.x;
        for (int t = t0; t < n_photons; t += ts)
            process(x[t], y[t], vals[t]);
    }

    __syncthreads();
    if (flush_mode == 2) {
        float* dst = flush_dst + (size_t)blockIdx.x * n_pixels;
        for (int k = threadIdx.x; k < n_pixels; k += blockDim.x)
            dst[k] = hist[k];
    } else {
        for (int k = threadIdx.x; k < n_pixels; k += blockDim.x) {
            float h = hist[k];
            if (h != 0.0f) atomicAdd(&flush_dst[k], h);
        }
    }
}

extern "C" void kernel_launch(void* const* d_in, const int* in_sizes, int n_in,
                              void* d_out, int out_size, void* d_ws, size_t ws_size,
                              hipStream_t stream) {
    const float* x      = (const float*)d_in[0];
    const float* y      = (const float*)d_in[1];
    const float* vals   = (const float*)d_in[2];
    const float* hexs   = (const float*)d_in[4];
    const float* qoff   = (const float*)d_in[5];
    const float* roff   = (const float*)d_in[6];
    const int*   qmin   = (const int*)d_in[7];
    const int*   rmin   = (const int*)d_in[8];

    const int n_photons = in_sizes[0];
    const int lut_elems = in_sizes[3];
    const int Q  = (int)(0.5 + sqrt((double)lut_elems));  // 49
    const int Rh = (Q - 1) / 2;                           // 24
    const int n_pixels = out_size;

    float* out = (float*)d_out;
    float* partials = (float*)d_ws;

    const size_t lds_bytes = (size_t)n_pixels * sizeof(float);
    const size_t part_elems = (size_t)BIN_BLOCKS * (size_t)n_pixels;

    if (ws_size >= part_elems * sizeof(float)) {
        hex_zero_kernel<<<(n_pixels + 255) / 256, 256, 0, stream>>>(out, n_pixels);
        hex_bin_kernel<<<BIN_BLOCKS, BIN_THREADS, lds_bytes, stream>>>(
            x, y, vals, hexs, qoff, roff, qmin, rmin,
            Rh, n_pixels, n_photons, partials, 2);
        dim3 rgrid((n_pixels + 255) / 256, BIN_BLOCKS / RED_GROUP);
        hex_reduce_kernel<<<rgrid, 256, 0, stream>>>(
            partials, out, n_pixels, BIN_BLOCKS);
    } else {
        hex_zero_kernel<<<(n_pixels + 255) / 256, 256, 0, stream>>>(out, n_pixels);
        hex_bin_kernel<<<BIN_BLOCKS, BIN_THREADS, lds_bytes, stream>>>(
            x, y, vals, hexs, qoff, roff, qmin, rmin,
            Rh, n_pixels, n_photons, out, 0);
    }
}